// Round 1
// baseline (56.964 us; speedup 1.0000x reference)
//
#include <hip/hip_runtime.h>
#include <math.h>

// MultiTaskLoss: fused single-pass reduction over B=4M samples.
// Inputs (f32 unless noted): pred_gps[B,2], true_lat[B], true_lon[B],
// pred_time[B,2], hour[B], minute[B], orient_logits[B,8], orientation[B] i32,
// pred_altitude[B,1], altitude[B], gps_scale[2], gps_offset[2].
// Output: 5 f32 scalars {total, gps, time, orient, alt}.

constexpr int GRID  = 1024;
constexpr int BLOCK = 256;
constexpr float RADF = 0.017453292519943295f;  // pi/180

__global__ void __launch_bounds__(BLOCK) mtl_partials(
    const float2* __restrict__ pred_gps,
    const float*  __restrict__ true_lat,
    const float*  __restrict__ true_lon,
    const float2* __restrict__ pred_time,
    const float*  __restrict__ hour,
    const float*  __restrict__ minute,
    const float4* __restrict__ logits4,    // 2 float4 per sample
    const int*    __restrict__ orient,
    const float*  __restrict__ pred_alt,
    const float*  __restrict__ alt,
    const float*  __restrict__ gps_scale,
    const float*  __restrict__ gps_offset,
    double*       __restrict__ partials,   // [4][GRID]
    int B)
{
    const float s0 = gps_scale[0],  s1 = gps_scale[1];
    const float o0 = gps_offset[0], o1 = gps_offset[1];

    float ag = 0.f, at = 0.f, ao = 0.f, aa = 0.f;

    int tid    = blockIdx.x * blockDim.x + threadIdx.x;
    int stride = gridDim.x * blockDim.x;

    for (int i = tid; i < B; i += stride) {
        // ---- GPS haversine ----
        float2 pg = pred_gps[i];
        float plat = fmaf(pg.x, s0, o0) * RADF;
        float plon = fmaf(pg.y, s1, o1) * RADF;
        float tlat = fmaf(true_lat[i], s0, o0) * RADF;
        float tlon = fmaf(true_lon[i], s1, o1) * RADF;
        float sdla = __sinf(0.5f * (plat - tlat));
        float sdlo = __sinf(0.5f * (plon - tlon));
        float a = sdla * sdla + __cosf(tlat) * __cosf(plat) * (sdlo * sdlo);
        a = fminf(fmaxf(a, 0.f), 1.f);
        ag += 6371.0f * (2.0f * asinf(sqrtf(a)));

        // ---- time MSE (mean over B*2 elements, divide later) ----
        float2 pt = pred_time[i];
        float dh = pt.x - hour[i];
        float dm = pt.y - minute[i];
        at += dh * dh + dm * dm;

        // ---- orientation NLL: lse(logits) - logits[k] ----
        float4 l0 = logits4[2 * i];
        float4 l1 = logits4[2 * i + 1];
        float m = fmaxf(fmaxf(fmaxf(l0.x, l0.y), fmaxf(l0.z, l0.w)),
                        fmaxf(fmaxf(l1.x, l1.y), fmaxf(l1.z, l1.w)));
        float se = __expf(l0.x - m) + __expf(l0.y - m) +
                   __expf(l0.z - m) + __expf(l0.w - m) +
                   __expf(l1.x - m) + __expf(l1.y - m) +
                   __expf(l1.z - m) + __expf(l1.w - m);
        float lse = m + __logf(se);
        int k = orient[i];
        float lk = (k < 4)
            ? ((k == 0) ? l0.x : (k == 1) ? l0.y : (k == 2) ? l0.z : l0.w)
            : ((k == 4) ? l1.x : (k == 5) ? l1.y : (k == 6) ? l1.z : l1.w);
        ao += lse - lk;

        // ---- altitude MSE ----
        float da = pred_alt[i] - alt[i];
        aa += da * da;
    }

    // ---- wave reduce (64 lanes) ----
    #pragma unroll
    for (int off = 32; off > 0; off >>= 1) {
        ag += __shfl_down(ag, off, 64);
        at += __shfl_down(at, off, 64);
        ao += __shfl_down(ao, off, 64);
        aa += __shfl_down(aa, off, 64);
    }

    __shared__ double sm[4][4];  // [wave][loss]
    int lane = threadIdx.x & 63;
    int wave = threadIdx.x >> 6;
    if (lane == 0) {
        sm[wave][0] = (double)ag;
        sm[wave][1] = (double)at;
        sm[wave][2] = (double)ao;
        sm[wave][3] = (double)aa;
    }
    __syncthreads();
    if (threadIdx.x < 4) {  // thread k handles loss k
        double s = sm[0][threadIdx.x] + sm[1][threadIdx.x] +
                   sm[2][threadIdx.x] + sm[3][threadIdx.x];
        partials[threadIdx.x * gridDim.x + blockIdx.x] = s;
    }
}

__global__ void __launch_bounds__(256) mtl_final(
    const double* __restrict__ partials,  // [4][GRID]
    float* __restrict__ out, int G, int B)
{
    int t = threadIdx.x;
    double v[4];
    #pragma unroll
    for (int k = 0; k < 4; ++k) {
        double s = 0.0;
        for (int b = t; b < G; b += 256) s += partials[k * G + b];
        v[k] = s;
    }
    #pragma unroll
    for (int off = 32; off > 0; off >>= 1) {
        #pragma unroll
        for (int k = 0; k < 4; ++k) v[k] += __shfl_down(v[k], off, 64);
    }
    __shared__ double sm[4][4];
    int lane = t & 63, wave = t >> 6;
    if (lane == 0) {
        #pragma unroll
        for (int k = 0; k < 4; ++k) sm[wave][k] = v[k];
    }
    __syncthreads();
    if (t == 0) {
        double g  = 0, tm = 0, od = 0, al = 0;
        #pragma unroll
        for (int w = 0; w < 4; ++w) {
            g += sm[w][0]; tm += sm[w][1]; od += sm[w][2]; al += sm[w][3];
        }
        double gps    = g  / (double)B;
        double timeL  = tm / (2.0 * (double)B);
        double orient = od / (double)B;
        double altL   = al / (double)B;
        double total  = gps + 0.5 * timeL + 0.3 * orient + 0.2 * altL;
        out[0] = (float)total;
        out[1] = (float)gps;
        out[2] = (float)timeL;
        out[3] = (float)orient;
        out[4] = (float)altL;
    }
}

extern "C" void kernel_launch(void* const* d_in, const int* in_sizes, int n_in,
                              void* d_out, int out_size, void* d_ws, size_t ws_size,
                              hipStream_t stream) {
    const float2* pred_gps   = (const float2*)d_in[0];
    const float*  true_lat   = (const float*)d_in[1];
    const float*  true_lon   = (const float*)d_in[2];
    const float2* pred_time  = (const float2*)d_in[3];
    const float*  hour       = (const float*)d_in[4];
    const float*  minute     = (const float*)d_in[5];
    const float4* logits4    = (const float4*)d_in[6];
    const int*    orient     = (const int*)d_in[7];
    const float*  pred_alt   = (const float*)d_in[8];
    const float*  alt        = (const float*)d_in[9];
    const float*  gps_scale  = (const float*)d_in[10];
    const float*  gps_offset = (const float*)d_in[11];

    int B = in_sizes[1];  // true_lat has B elements
    double* partials = (double*)d_ws;  // needs 4*GRID*8 = 32 KiB

    mtl_partials<<<GRID, BLOCK, 0, stream>>>(
        pred_gps, true_lat, true_lon, pred_time, hour, minute,
        logits4, orient, pred_alt, alt, gps_scale, gps_offset,
        partials, B);
    mtl_final<<<1, 256, 0, stream>>>(partials, (float*)d_out, GRID, B);
}